// Round 1
// baseline (494.113 us; speedup 1.0000x reference)
//
#include <hip/hip_runtime.h>
#include <hip/hip_bf16.h>
#include <math.h>

#define B_     16
#define C_     256
#define H_     56
#define W_     56
#define HEADS_ 4
#define CPER_  64
#define R_     16
#define HW_    (H_*W_)      // 3136
#define BN_EPS_ 1e-5f
#define YT  4               // output rows per conv block
#define CHK 8               // channels staged per LDS chunk

// ---------------- K1: BN(inference) + ReLU -> xn, plus global avg pool ----------------
__global__ __launch_bounds__(256) void k_bn_pool(
    const float* __restrict__ x,
    const float* __restrict__ gamma, const float* __restrict__ beta,
    const float* __restrict__ mean,  const float* __restrict__ var,
    float* __restrict__ xn, float* __restrict__ xavg)
{
    int plane = blockIdx.x;           // b*C + c
    int c = plane & (C_ - 1);
    int tid = threadIdx.x;
    float s = gamma[c] * rsqrtf(var[c] + BN_EPS_);
    float t = beta[c] - mean[c] * s;

    const float4* xin = (const float4*)(x  + (size_t)plane * HW_);
    float4*       xo  = (float4*)      (xn + (size_t)plane * HW_);
    float sum = 0.f;
    for (int i = tid; i < HW_/4; i += 256) {
        float4 v = xin[i];
        v.x = fmaxf(fmaf(v.x, s, t), 0.f);
        v.y = fmaxf(fmaf(v.y, s, t), 0.f);
        v.z = fmaxf(fmaf(v.z, s, t), 0.f);
        v.w = fmaxf(fmaf(v.w, s, t), 0.f);
        xo[i] = v;
        sum += v.x + v.y + v.z + v.w;
    }
    // wave64 shuffle reduce, then cross-wave via LDS
    for (int off = 32; off > 0; off >>= 1) sum += __shfl_down(sum, off, 64);
    __shared__ float sred[4];
    int lane = tid & 63, wv = tid >> 6;
    if (lane == 0) sred[wv] = sum;
    __syncthreads();
    if (tid == 0) {
        float tot = sred[0] + sred[1] + sred[2] + sred[3];
        xavg[plane] = tot * (1.f / HW_);
    }
}

// ---------------- K2b: weight transpose conv_w[h][j][c][9] -> wt[h][c][j][9] ----------
__global__ __launch_bounds__(256) void k_wtrans(const float* __restrict__ w,
                                                float* __restrict__ wt)
{
    int i = blockIdx.x * 256 + threadIdx.x;
    if (i >= HEADS_ * CPER_ * C_ * 9) return;
    int t = i % 9;
    int j = (i / 9) % CPER_;
    int c = (i / (9 * CPER_)) % C_;
    int h = i / (9 * CPER_ * C_);
    wt[i] = w[((size_t)(h * CPER_ + j) * C_ + c) * 9 + t];  // write coalesced
}

// ---------------- K2: SE gate, exact rank-k threshold, compaction, lasso ---------------
__global__ __launch_bounds__(256) void k_se(
    const float* __restrict__ xavg,
    const float* __restrict__ fc1, const float* __restrict__ fc2,
    const float* __restrict__ fc2b, const int* __restrict__ kptr,
    float* __restrict__ maskc, int* __restrict__ act_idx,
    int* __restrict__ act_cnt, float* __restrict__ lasso)
{
    int hb = blockIdx.x;              // h*B + b
    int h = hb / B_, b = hb - h * B_;
    int tid = threadIdx.x;            // = channel c

    __shared__ float sav[C_], sy1[R_], smask[C_], sred[4], sthr;
    __shared__ int scnt;

    sav[tid] = xavg[b * C_ + tid];
    if (tid == 0) scnt = 0;
    __syncthreads();

    if (tid < R_) {                   // y1[r] = relu(<xavg, fc1[h][r][:]>)
        const float* w = fc1 + (size_t)(h * R_ + tid) * C_;
        float acc = 0.f;
        for (int c2 = 0; c2 < C_; ++c2) acc = fmaf(sav[c2], w[c2], acc);
        sy1[tid] = fmaxf(acc, 0.f);
    }
    __syncthreads();

    const float* w2 = fc2 + (size_t)(h * C_ + tid) * R_;
    float acc = fc2b[h * C_ + tid];
    for (int r = 0; r < R_; ++r) acc = fmaf(sy1[r], w2[r], acc);
    float m = fmaxf(acc, 0.f);        // mask[h][b][c]
    smask[tid] = m;
    __syncthreads();

    // lasso partial (pre-threshold mask)
    float ls = m;
    for (int off = 32; off > 0; off >>= 1) ls += __shfl_down(ls, off, 64);
    int lane = tid & 63, wv = tid >> 6;
    if (lane == 0) sred[wv] = ls;

    // exact selection of the k-th smallest (ties handled like a stable sort)
    int cl = 0, ce = 0;
    for (int j = 0; j < C_; ++j) {
        float vj = smask[j];
        cl += (vj < m);
        ce += (vj == m);
    }
    if (tid == 0) sthr = -1e30f;
    __syncthreads();
    int k = kptr[0];
    if (k > 0 && cl <= k - 1 && (k - 1) < cl + ce) sthr = m;  // all writers hold same value
    __syncthreads();

    float thr = sthr;
    float mc = (m <= thr) ? 0.f : m;
    maskc[hb * C_ + tid] = mc;
    if (mc != 0.f) {
        int p = atomicAdd(&scnt, 1);  // order-free compaction (sum order irrelevant)
        act_idx[hb * 256 + p] = tid;
    }
    __syncthreads();
    if (tid == 0) {
        act_cnt[hb] = scnt;
        atomicAdd(lasso, (sred[0] + sred[1] + sred[2] + sred[3]) * (1.f / (B_ * C_)));
    }
}

// ---------------- K3: grouped conv over ACTIVE channels only ---------------------------
// block = (y-tile of 4 rows, h, b); 256 thr: lane=x (56 valid), wave=16-j group.
// Inner K: active channels (<=64) x 9 taps. Weights via wave-uniform scalar loads.
__global__ __launch_bounds__(256) void k_conv(
    const float* __restrict__ xn, const float* __restrict__ wt,
    const float* __restrict__ maskc, const int* __restrict__ act_idx,
    const int* __restrict__ act_cnt, float* __restrict__ out)
{
    int yt = blockIdx.x;              // 0..13
    int h  = blockIdx.y;              // 0..3
    int b  = blockIdx.z;              // 0..15
    int tid  = threadIdx.x;
    int lane = tid & 63;
    int wv   = tid >> 6;
    int x    = lane;                  // output x
    bool active = (x < W_);
    int xr = active ? x : (W_ - 1);   // clamp so LDS reads stay in [0,58)
    int y0 = yt * YT;
    int hb = h * B_ + b;
    int jb = wv * 16;
    int jbu = __builtin_amdgcn_readfirstlane(jb);

    __shared__ int   s_act[256];
    __shared__ float s_mv[256];
    __shared__ float smem_in[CHK][YT + 2][W_ + 2];   // 8*6*58*4 = 11136 B

    int cnt = act_cnt[hb];            // wave-uniform
    for (int t = tid; t < cnt; t += 256) {
        int c = act_idx[hb * 256 + t];
        s_act[t] = c;
        s_mv[t]  = maskc[hb * C_ + c];
    }

    float accv[16][YT];
    #pragma unroll
    for (int j = 0; j < 16; ++j)
        #pragma unroll
        for (int yr = 0; yr < YT; ++yr) accv[j][yr] = 0.f;

    for (int c0 = 0; c0 < cnt; c0 += CHK) {
        int nch = min(CHK, cnt - c0);
        __syncthreads();              // prev compute done; s_act ready (1st iter)
        // stage nch channels x 6 rows x 58 cols, mask folded in
        int total = nch * (YT + 2) * (W_ + 2);
        for (int e = tid; e < total; e += 256) {
            int ch  = e / ((YT + 2) * (W_ + 2));
            int rem = e - ch * ((YT + 2) * (W_ + 2));
            int r   = rem / (W_ + 2);
            int col = rem - r * (W_ + 2);
            int gy = y0 + r - 1;
            int gx = col - 1;
            float v = 0.f;
            if (gy >= 0 && gy < H_ && gx >= 0 && gx < W_)
                v = xn[(((size_t)b * C_ + s_act[c0 + ch]) * H_ + gy) * W_ + gx]
                    * s_mv[c0 + ch];
            smem_in[ch][r][col] = v;
        }
        __syncthreads();

        for (int ch = 0; ch < nch; ++ch) {
            int cu = __builtin_amdgcn_readfirstlane(s_act[c0 + ch]);
            const float* wb = wt + ((size_t)(h * C_ + cu) * CPER_ + jbu) * 9;
            float in[YT + 2][3];
            #pragma unroll
            for (int r = 0; r < YT + 2; ++r) {
                in[r][0] = smem_in[ch][r][xr];
                in[r][1] = smem_in[ch][r][xr + 1];
                in[r][2] = smem_in[ch][r][xr + 2];
            }
            #pragma unroll
            for (int j = 0; j < 16; ++j) {
                float w[9];
                #pragma unroll
                for (int t = 0; t < 9; ++t) w[t] = wb[j * 9 + t];  // scalar loads
                #pragma unroll
                for (int yr = 0; yr < YT; ++yr) {
                    float a = accv[j][yr];
                    #pragma unroll
                    for (int r = 0; r < 3; ++r)
                        #pragma unroll
                        for (int kx = 0; kx < 3; ++kx)
                            a = fmaf(in[yr + r][kx], w[r * 3 + kx], a);
                    accv[j][yr] = a;
                }
            }
        }
    }

    if (active) {
        #pragma unroll
        for (int j = 0; j < 16; ++j) {
            int oc = (jb + j) * HEADS_ + h;    // final interleave: channel = j*heads + h
            #pragma unroll
            for (int yr = 0; yr < YT; ++yr)
                out[(((size_t)b * C_ + oc) * H_ + (y0 + yr)) * W_ + x] = accv[j][yr];
        }
    }
}

// ---------------- launch ----------------------------------------------------------------
extern "C" void kernel_launch(void* const* d_in, const int* in_sizes, int n_in,
                              void* d_out, int out_size, void* d_ws, size_t ws_size,
                              hipStream_t stream)
{
    const float* x     = (const float*)d_in[0];
    const float* gamma = (const float*)d_in[1];
    const float* beta  = (const float*)d_in[2];
    const float* mean  = (const float*)d_in[3];
    const float* var   = (const float*)d_in[4];
    const float* fc1   = (const float*)d_in[5];
    const float* fc2   = (const float*)d_in[6];
    const float* fc2b  = (const float*)d_in[7];
    const float* convw = (const float*)d_in[8];
    const int*   kptr  = (const int*)d_in[9];

    float* out   = (float*)d_out;
    float* lasso = out + (size_t)B_ * C_ * HW_;   // output 1 (scalar)

    char* ws = (char*)d_ws;
    size_t off = 0;
    float* xn    = (float*)(ws + off); off += (size_t)B_ * C_ * HW_ * 4;   // 51.4 MB
    float* xavg  = (float*)(ws + off); off += (size_t)B_ * C_ * 4;
    float* maskc = (float*)(ws + off); off += (size_t)HEADS_ * B_ * C_ * 4;
    int*   aidx  = (int*)  (ws + off); off += (size_t)HEADS_ * B_ * 256 * 4;
    int*   acnt  = (int*)  (ws + off); off += (size_t)HEADS_ * B_ * 4;
    off = (off + 255) & ~(size_t)255;
    float* wt    = (float*)(ws + off); off += (size_t)HEADS_ * C_ * CPER_ * 9 * 4;

    hipMemsetAsync(lasso, 0, 4, stream);   // zero before K2's atomicAdd

    k_bn_pool<<<B_ * C_, 256, 0, stream>>>(x, gamma, beta, mean, var, xn, xavg);
    k_wtrans<<<(HEADS_ * CPER_ * C_ * 9 + 255) / 256, 256, 0, stream>>>(convw, wt);
    k_se<<<HEADS_ * B_, 256, 0, stream>>>(xavg, fc1, fc2, fc2b, kptr,
                                          maskc, aidx, acnt, lasso);
    k_conv<<<dim3(H_ / YT, HEADS_, B_), 256, 0, stream>>>(xn, wt, maskc, aidx, acnt, out);
}

// Round 2
// 261.824 us; speedup vs baseline: 1.8872x; 1.8872x over previous
//
#include <hip/hip_runtime.h>
#include <hip/hip_bf16.h>
#include <math.h>

#define B_     16
#define C_     256
#define H_     56
#define W_     56
#define HEADS_ 4
#define CPER_  64
#define R_     16
#define HW_    (H_*W_)      // 3136
#define BN_EPS_ 1e-5f

typedef short bf16x8 __attribute__((ext_vector_type(8)));
typedef float f32x4  __attribute__((ext_vector_type(4)));

__device__ inline unsigned short f2bf(float f) {
    unsigned int u = __builtin_bit_cast(unsigned int, f);
    u += 0x7fffu + ((u >> 16) & 1u);          // RNE (finite inputs only)
    return (unsigned short)(u >> 16);
}

// ---------------- K1: BN+ReLU, transpose to xnT[b][y][x][c] bf16, row pool partials ----
__global__ __launch_bounds__(256) void k_bn_t(
    const float* __restrict__ x,
    const float* __restrict__ gamma, const float* __restrict__ beta,
    const float* __restrict__ mean,  const float* __restrict__ var,
    short* __restrict__ xnT, float* __restrict__ pools)
{
    int y = blockIdx.x, b = blockIdx.y;
    int tid = threadIdx.x, lane = tid & 63, w = tid >> 6;
    __shared__ unsigned short T[64 * 258];    // [x 64][c 256+2 pad] -> conflict-free both ways

    for (int cc = 0; cc < 64; ++cc) {
        int c = w * 64 + cc;                  // wave-uniform channel
        float s = gamma[c] * rsqrtf(var[c] + BN_EPS_);
        float t = fmaf(-mean[c], s, beta[c]);
        float v = 0.f;
        if (lane < W_) v = x[(((size_t)b * C_ + c) * H_ + y) * W_ + lane];
        v = fmaxf(fmaf(v, s, t), 0.f);
        if (lane >= W_) v = 0.f;              // zero AFTER bn: relu(t) may be >0
        T[lane * 258 + c] = f2bf(v);
        float ps = v;                         // fp32 pool (matches ref precision)
        for (int off = 32; off; off >>= 1) ps += __shfl_down(ps, off, 64);
        if (lane == 0) pools[((size_t)b * H_ + y) * C_ + c] = ps;
    }
    __syncthreads();

    int cp = tid & 127, xh = tid >> 7;
    for (int x0 = 0; x0 < W_; x0 += 2) {
        int xx = x0 + xh;
        unsigned int lo = T[xx * 258 + 2 * cp], hi = T[xx * 258 + 2 * cp + 1];
        ((unsigned int*)xnT)[(((size_t)b * H_ + y) * W_ + xx) * 128 + cp] = lo | (hi << 16);
    }
}

// ---------------- K1b: deterministic pool finish --------------------------------------
__global__ __launch_bounds__(256) void k_pool2(const float* __restrict__ pools,
                                               float* __restrict__ xavg)
{
    int b = blockIdx.x, c = threadIdx.x;
    float s = 0.f;
    for (int y = 0; y < H_; ++y) s += pools[((size_t)b * H_ + y) * C_ + c];
    xavg[b * C_ + c] = s * (1.f / HW_);
}

// ---------------- K2a: conv_w[h][j][c][t] -> wt2f[h][t][j][c] (fp32, c innermost) -----
__global__ __launch_bounds__(256) void k_wt2(const float* __restrict__ w,
                                             float* __restrict__ wt2f)
{
    int i = blockIdx.x * 256 + threadIdx.x;
    if (i >= HEADS_ * 9 * CPER_ * C_) return;
    int c = i & 255, j = (i >> 8) & 63, ht = i >> 14;
    int h = ht / 9, t = ht - h * 9;
    wt2f[i] = w[((size_t)((h * CPER_ + j) * C_ + c)) * 9 + t];
}

// ---------------- K2: SE gate, exact rank-k threshold, compaction, lasso ---------------
__global__ __launch_bounds__(256) void k_se(
    const float* __restrict__ xavg,
    const float* __restrict__ fc1, const float* __restrict__ fc2,
    const float* __restrict__ fc2b, const int* __restrict__ kptr,
    float* __restrict__ maskc, int* __restrict__ act_idx,
    int* __restrict__ act_cnt, float* __restrict__ lasso)
{
    int hb = blockIdx.x;              // h*B + b
    int h = hb / B_, b = hb - h * B_;
    int tid = threadIdx.x;            // = channel c

    __shared__ float sav[C_], sy1[R_], smask[C_], sred[4], sthr;
    __shared__ int scnt;

    sav[tid] = xavg[b * C_ + tid];
    if (tid == 0) scnt = 0;
    __syncthreads();

    if (tid < R_) {
        const float* w = fc1 + (size_t)(h * R_ + tid) * C_;
        float acc = 0.f;
        for (int c2 = 0; c2 < C_; ++c2) acc = fmaf(sav[c2], w[c2], acc);
        sy1[tid] = fmaxf(acc, 0.f);
    }
    __syncthreads();

    const float* w2 = fc2 + (size_t)(h * C_ + tid) * R_;
    float acc = fc2b[h * C_ + tid];
    for (int r = 0; r < R_; ++r) acc = fmaf(sy1[r], w2[r], acc);
    float m = fmaxf(acc, 0.f);
    smask[tid] = m;
    __syncthreads();

    float ls = m;
    for (int off = 32; off > 0; off >>= 1) ls += __shfl_down(ls, off, 64);
    int lane = tid & 63, wv = tid >> 6;
    if (lane == 0) sred[wv] = ls;

    int cl = 0, ce = 0;
    for (int j = 0; j < C_; ++j) {
        float vj = smask[j];
        cl += (vj < m);
        ce += (vj == m);
    }
    if (tid == 0) sthr = -1e30f;
    __syncthreads();
    int k = kptr[0];
    if (k > 0 && cl <= k - 1 && (k - 1) < cl + ce) sthr = m;
    __syncthreads();

    float thr = sthr;
    float mc = (m <= thr) ? 0.f : m;
    maskc[hb * C_ + tid] = mc;
    if (mc != 0.f) {
        int p = atomicAdd(&scnt, 1);
        act_idx[hb * 256 + p] = tid;
    }
    __syncthreads();
    if (tid == 0) {
        act_cnt[hb] = scnt;
        atomicAdd(lasso, (sred[0] + sred[1] + sred[2] + sred[3]) * (1.f / (B_ * C_)));
    }
}

// ---------------- K2c: compact+mask weights -> Wc[hb][t][j][c'] bf16 (zero padded) -----
__global__ __launch_bounds__(256) void k_wgather(
    const float* __restrict__ wt2f, const float* __restrict__ maskc,
    const int* __restrict__ aidx, const int* __restrict__ acnt,
    short* __restrict__ Wc)
{
    int t = blockIdx.x, hb = blockIdx.y;
    int h = hb >> 4;
    int tid = threadIdx.x;
    int cnt = acnt[hb];
    __shared__ int s_act[64];
    __shared__ float s_mv[64];
    if (tid < 64) {
        int a = (tid < cnt) ? aidx[hb * 256 + tid] : 0;
        s_act[tid] = a;
        s_mv[tid]  = (tid < cnt) ? maskc[hb * C_ + a] : 0.f;
    }
    __syncthreads();
    const float* wsrc = wt2f + (size_t)(h * 9 + t) * (CPER_ * C_);
    short* wdst = Wc + (size_t)(hb * 9 + t) * (CPER_ * 64);
    for (int it = 0; it < 16; ++it) {
        int e = it * 256 + tid;
        int cp = e & 63, j = e >> 6;
        float v = wsrc[j * C_ + s_act[cp]] * s_mv[cp];   // mask folded into weight
        wdst[e] = (short)f2bf(v);
    }
}

// ---------------- K3: implicit-GEMM bf16 MFMA conv -------------------------------------
// block = (band of 4 rows, h, b); wave w = row. 16x16x32 MFMA: m=j(16), n=x(16), k=c(32).
// LDS sX[6 rows][66 cols][64 ch] bf16 with channel-rotate swizzle slot=(c+8*(col&7))&63:
//   - B-frag ds_read_b128 16B-aligned, 8 dwords/bank (optimal floor)
//   - staging b32 writes conflict-free; staging global reads hit a 512B window (xnT layout)
__global__ __launch_bounds__(256, 3) void k_conv(
    const short* __restrict__ xnT, const short* __restrict__ Wc,
    const int* __restrict__ aidx, const int* __restrict__ acnt,
    float* __restrict__ out)
{
    int band = blockIdx.x, h = blockIdx.y, b = blockIdx.z;
    int hb = h * B_ + b;
    int tid = threadIdx.x, lane = tid & 63, w = tid >> 6;
    int y0 = band * 4;
    int cnt = acnt[hb];
    int cntp = (cnt + 31) & ~31;

    __shared__ short sX[6 * 66 * 64];         // 50688 B
    __shared__ int s_act[64];
    if (tid < 64) s_act[tid] = (tid < cnt) ? aidx[hb * 256 + tid] : 0;
    __syncthreads();

    {   // stage input tile (unmasked; mask lives in Wc)
        const short* xb = xnT + (size_t)b * HW_ * C_;
        int c2 = (tid & 31) * 2, colw = tid >> 5;
        unsigned int* sXu = (unsigned int*)sX;
        for (int row = 0; row < 6; ++row) {
            int gy = y0 + row - 1;
            bool yok = (gy >= 0 && gy < H_);
            for (int colg = 0; colg < 9; ++colg) {
                int col = colg * 8 + colw;
                if (col >= 66) break;
                int gx = col - 1;
                unsigned int val = 0;
                if (yok && gx >= 0 && gx < W_) {
                    int base = (gy * W_ + gx) * C_;
                    unsigned int lo = (c2     < cnt) ? (unsigned short)xb[base + s_act[c2]]     : 0u;
                    unsigned int hi = (c2 + 1 < cnt) ? (unsigned short)xb[base + s_act[c2 + 1]] : 0u;
                    val = lo | (hi << 16);
                }
                int slot = (c2 + ((col & 7) << 3)) & 63;
                sXu[(row * 66 + col) * 32 + (slot >> 1)] = val;
            }
        }
    }
    __syncthreads();

    f32x4 acc[4][4];
    #pragma unroll
    for (int i = 0; i < 4; ++i)
        #pragma unroll
        for (int j = 0; j < 4; ++j)
            #pragma unroll
            for (int r = 0; r < 4; ++r) acc[i][j][r] = 0.f;

    int m = lane & 15, q = lane >> 4;
    const unsigned int* sXu = (const unsigned int*)sX;
    const short* Wh = Wc + (size_t)hb * 9 * 4096;
    int yrow = y0 + w;

    for (int t = 0; t < 9; ++t) {
        int dy = t / 3 - 1, dx = t - (t / 3) * 3 - 1;
        int srow = w + dy + 1;
        int coln = m + dx + 1;
        int sb8 = (coln & 7) << 3;            // col&7 is xt-invariant (xt*16 ≡ 0 mod 8)
        const short* Wt = Wh + t * 4096 + m * 64 + q * 8;
        int ub = (srow * 66 + coln) * 32;
        for (int c0 = 0; c0 < cntp; c0 += 32) {
            bf16x8 aF[4], bF[4];
            #pragma unroll
            for (int jt = 0; jt < 4; ++jt)
                aF[jt] = *(const bf16x8*)(Wt + jt * 1024 + c0);
            int slot = (c0 + q * 8 + sb8) & 63;
            #pragma unroll
            for (int xt = 0; xt < 4; ++xt)
                bF[xt] = *(const bf16x8*)&sXu[ub + xt * 512 + (slot >> 1)];
            #pragma unroll
            for (int jt = 0; jt < 4; ++jt)
                #pragma unroll
                for (int xt = 0; xt < 4; ++xt)
                    acc[jt][xt] = __builtin_amdgcn_mfma_f32_16x16x32_bf16(
                        aF[jt], bF[xt], acc[jt][xt], 0, 0, 0);
        }
    }

    #pragma unroll
    for (int xt = 0; xt < 4; ++xt) {
        int xx = xt * 16 + m;
        if (xx < W_) {
            #pragma unroll
            for (int jt = 0; jt < 4; ++jt)
                #pragma unroll
                for (int r = 0; r < 4; ++r) {
                    int j = jt * 16 + q * 4 + r;          // D: row = quad*4 + reg
                    int oc = j * HEADS_ + h;              // head interleave
                    out[(((size_t)b * C_ + oc) * H_ + yrow) * W_ + xx] = acc[jt][xt][r];
                }
        }
    }
}

// ---------------- launch ----------------------------------------------------------------
extern "C" void kernel_launch(void* const* d_in, const int* in_sizes, int n_in,
                              void* d_out, int out_size, void* d_ws, size_t ws_size,
                              hipStream_t stream)
{
    const float* x     = (const float*)d_in[0];
    const float* gamma = (const float*)d_in[1];
    const float* beta  = (const float*)d_in[2];
    const float* mean  = (const float*)d_in[3];
    const float* var   = (const float*)d_in[4];
    const float* fc1   = (const float*)d_in[5];
    const float* fc2   = (const float*)d_in[6];
    const float* fc2b  = (const float*)d_in[7];
    const float* convw = (const float*)d_in[8];
    const int*   kptr  = (const int*)d_in[9];

    float* out   = (float*)d_out;
    float* lasso = out + (size_t)B_ * C_ * HW_;

    char* ws = (char*)d_ws;
    size_t off = 0;
    short* xnT  = (short*)(ws + off); off += (size_t)B_ * HW_ * C_ * 2;      // 25.7 MB
    off = (off + 255) & ~(size_t)255;
    float* pools = (float*)(ws + off); off += (size_t)B_ * H_ * C_ * 4;      // 0.92 MB
    float* xavg  = (float*)(ws + off); off += (size_t)B_ * C_ * 4;
    float* maskc = (float*)(ws + off); off += (size_t)HEADS_ * B_ * C_ * 4;
    int*   aidx  = (int*)  (ws + off); off += (size_t)HEADS_ * B_ * 256 * 4;
    int*   acnt  = (int*)  (ws + off); off += (size_t)HEADS_ * B_ * 4;
    off = (off + 255) & ~(size_t)255;
    float* wt2f  = (float*)(ws + off); off += (size_t)HEADS_ * 9 * CPER_ * C_ * 4;  // 2.36 MB
    off = (off + 255) & ~(size_t)255;
    short* Wc    = (short*)(ws + off); off += (size_t)HEADS_ * B_ * 9 * CPER_ * 64 * 2; // 4.72 MB

    hipMemsetAsync(lasso, 0, 4, stream);

    k_bn_t<<<dim3(H_, B_), 256, 0, stream>>>(x, gamma, beta, mean, var, xnT, pools);
    k_wt2<<<(HEADS_ * 9 * CPER_ * C_ + 255) / 256, 256, 0, stream>>>(convw, wt2f);
    k_pool2<<<B_, 256, 0, stream>>>(pools, xavg);
    k_se<<<HEADS_ * B_, 256, 0, stream>>>(xavg, fc1, fc2, fc2b, kptr,
                                          maskc, aidx, acnt, lasso);
    k_wgather<<<dim3(9, HEADS_ * B_), 256, 0, stream>>>(wt2f, maskc, aidx, acnt, Wc);
    k_conv<<<dim3(H_ / 4, HEADS_, B_), 256, 0, stream>>>(xnT, Wc, aidx, acnt, out);
}

// Round 3
// 202.843 us; speedup vs baseline: 2.4359x; 1.2908x over previous
//
#include <hip/hip_runtime.h>
#include <hip/hip_bf16.h>
#include <math.h>

#define B_     16
#define C_     256
#define H_     56
#define W_     56
#define HEADS_ 4
#define CPER_  64
#define R_     16
#define HW_    (H_*W_)      // 3136
#define BN_EPS_ 1e-5f

typedef short bf16x8 __attribute__((ext_vector_type(8)));
typedef float f32x4  __attribute__((ext_vector_type(4)));

__device__ inline unsigned short f2bf(float f) {
    unsigned int u = __builtin_bit_cast(unsigned int, f);
    u += 0x7fffu + ((u >> 16) & 1u);          // RNE (finite inputs only)
    return (unsigned short)(u >> 16);
}

// ---------------- K0: exact fp32 BN+ReLU+mean per (b,c) plane --------------------------
__global__ __launch_bounds__(64) void k_pool(
    const float* __restrict__ x,
    const float* __restrict__ gamma, const float* __restrict__ beta,
    const float* __restrict__ mean,  const float* __restrict__ var,
    float* __restrict__ xavg)
{
    int plane = blockIdx.x;                   // b*256 + c
    int c = plane & (C_ - 1);
    float s = gamma[c] * rsqrtf(var[c] + BN_EPS_);
    float t = fmaf(-mean[c], s, beta[c]);
    const float4* xp = (const float4*)(x + (size_t)plane * HW_);
    float sum = 0.f;
    for (int i = threadIdx.x; i < HW_ / 4; i += 64) {
        float4 v = xp[i];
        sum += fmaxf(fmaf(v.x, s, t), 0.f) + fmaxf(fmaf(v.y, s, t), 0.f)
             + fmaxf(fmaf(v.z, s, t), 0.f) + fmaxf(fmaf(v.w, s, t), 0.f);
    }
    for (int off = 32; off; off >>= 1) sum += __shfl_down(sum, off, 64);
    if (threadIdx.x == 0) xavg[plane] = sum * (1.f / HW_);
}

// ---------------- K2a: conv_w[h][j][c][t] -> wt2f[h][t][j][c] (fp32, c innermost) -----
__global__ __launch_bounds__(256) void k_wt2(const float* __restrict__ w,
                                             float* __restrict__ wt2f)
{
    int i = blockIdx.x * 256 + threadIdx.x;
    if (i >= HEADS_ * 9 * CPER_ * C_) return;
    int c = i & 255, j = (i >> 8) & 63, ht = i >> 14;
    int h = ht / 9, t = ht - h * 9;
    wt2f[i] = w[((size_t)((h * CPER_ + j) * C_ + c)) * 9 + t];
}

// ---------------- K2: SE gate, exact rank-k threshold, compaction, lasso ---------------
__global__ __launch_bounds__(256) void k_se(
    const float* __restrict__ xavg,
    const float* __restrict__ fc1, const float* __restrict__ fc2,
    const float* __restrict__ fc2b, const int* __restrict__ kptr,
    float* __restrict__ maskc, int* __restrict__ aidx64,
    int* __restrict__ act_cnt, float* __restrict__ lasso)
{
    int hb = blockIdx.x;              // h*B + b
    int h = hb / B_, b = hb - h * B_;
    int tid = threadIdx.x;            // = channel c

    __shared__ float sav[C_], sy1[R_], smask[C_], sred[4], sthr;
    __shared__ int scnt, s_ord[C_];

    sav[tid] = xavg[b * C_ + tid];
    if (tid == 0) scnt = 0;
    __syncthreads();

    if (tid < R_) {
        const float* w = fc1 + (size_t)(h * R_ + tid) * C_;
        float acc = 0.f;
        for (int c2 = 0; c2 < C_; ++c2) acc = fmaf(sav[c2], w[c2], acc);
        sy1[tid] = fmaxf(acc, 0.f);
    }
    __syncthreads();

    const float* w2 = fc2 + (size_t)(h * C_ + tid) * R_;
    float acc = fc2b[h * C_ + tid];
    for (int r = 0; r < R_; ++r) acc = fmaf(sy1[r], w2[r], acc);
    float m = fmaxf(acc, 0.f);
    smask[tid] = m;
    __syncthreads();

    float ls = m;
    for (int off = 32; off > 0; off >>= 1) ls += __shfl_down(ls, off, 64);
    int lane = tid & 63, wv = tid >> 6;
    if (lane == 0) sred[wv] = ls;

    int cl = 0, ce = 0;
    for (int j = 0; j < C_; ++j) {
        float vj = smask[j];
        cl += (vj < m);
        ce += (vj == m);
    }
    if (tid == 0) sthr = -1e30f;
    __syncthreads();
    int k = kptr[0];
    if (k > 0 && cl <= k - 1 && (k - 1) < cl + ce) sthr = m;
    __syncthreads();

    float thr = sthr;
    float mc = (m <= thr) ? 0.f : m;
    maskc[hb * C_ + tid] = mc;
    if (mc != 0.f) {
        int p = atomicAdd(&scnt, 1);          // order-free (all consumers use same list)
        s_ord[p] = tid;
    }
    __syncthreads();
    if (tid < 64) aidx64[hb * 64 + tid] = (tid < scnt) ? s_ord[tid] : 0;  // zero-padded
    if (tid == 0) {
        act_cnt[hb] = scnt;
        atomicAdd(lasso, (sred[0] + sred[1] + sred[2] + sred[3]) * (1.f / (B_ * C_)));
    }
}

// ---------------- K2c: compact+mask weights -> Wc[hb][t][j][c'] bf16 (zero padded) -----
__global__ __launch_bounds__(256) void k_wgather(
    const float* __restrict__ wt2f, const float* __restrict__ maskc,
    const int* __restrict__ aidx64, const int* __restrict__ acnt,
    short* __restrict__ Wc)
{
    int t = blockIdx.x, hb = blockIdx.y;
    int h = hb >> 4;
    int tid = threadIdx.x;
    int cnt = acnt[hb];
    __shared__ int s_act[64];
    __shared__ float s_mv[64];
    if (tid < 64) {
        int a = aidx64[hb * 64 + tid];
        s_act[tid] = a;
        s_mv[tid]  = (tid < cnt) ? maskc[hb * C_ + a] : 0.f;
    }
    __syncthreads();
    const float* wsrc = wt2f + (size_t)(h * 9 + t) * (CPER_ * C_);
    short* wdst = Wc + (size_t)(hb * 9 + t) * (CPER_ * 64);
    for (int it = 0; it < 16; ++it) {
        int e = it * 256 + tid;
        int cp = e & 63, j = e >> 6;
        float v = wsrc[j * C_ + s_act[cp]] * s_mv[cp];   // mask folded into weight
        wdst[e] = (short)f2bf(v);
    }
}

// ---------------- K1: BN+ReLU+bf16 + per-head channel compaction -> xc[hb][px][64] -----
__global__ __launch_bounds__(256) void k_bnc(
    const float* __restrict__ x,
    const float* __restrict__ gamma, const float* __restrict__ beta,
    const float* __restrict__ mean,  const float* __restrict__ var,
    const int* __restrict__ aidx64, short* __restrict__ xc)
{
    int y = blockIdx.x, b = blockIdx.y;
    int tid = threadIdx.x;
    __shared__ unsigned short T[W_ * 258];    // [x][c], +2 pad breaks stride-256 conflicts
    __shared__ float ss[C_], st[C_];
    __shared__ short sact[256];               // [h][64]

    {
        float s = gamma[tid] * rsqrtf(var[tid] + BN_EPS_);
        ss[tid] = s;
        st[tid] = fmaf(-mean[tid], s, beta[tid]);
        int h = tid >> 6, cp = tid & 63;
        sact[tid] = (short)aidx64[(h * B_ + b) * 64 + cp];
    }
    __syncthreads();

    const float* xrow = x + (size_t)b * C_ * HW_ + y * W_;
    for (int i = tid; i < C_ * 14; i += 256) {    // 14 float4 per channel row
        int c = i / 14, f = i - c * 14;
        float4 v = *(const float4*)(xrow + (size_t)c * HW_ + f * 4);
        float s = ss[c], t = st[c];
        int xb = f * 4;
        T[(xb + 0) * 258 + c] = f2bf(fmaxf(fmaf(v.x, s, t), 0.f));
        T[(xb + 1) * 258 + c] = f2bf(fmaxf(fmaf(v.y, s, t), 0.f));
        T[(xb + 2) * 258 + c] = f2bf(fmaxf(fmaf(v.z, s, t), 0.f));
        T[(xb + 3) * 258 + c] = f2bf(fmaxf(fmaf(v.w, s, t), 0.f));
    }
    __syncthreads();

    unsigned int* ob = (unsigned int*)xc;
    #pragma unroll
    for (int h = 0; h < HEADS_; ++h) {
        size_t obase = ((size_t)(h * B_ + b) * HW_ + (size_t)y * W_) * 32;
        for (int i = tid; i < W_ * 32; i += 256) {    // 56 px x 32 dwords, 7 iters
            int px = i >> 5, d = i & 31;
            unsigned int lo = T[px * 258 + sact[h * 64 + 2 * d]];
            unsigned int hi = T[px * 258 + sact[h * 64 + 2 * d + 1]];
            ob[obase + i] = lo | (hi << 16);
        }
    }
}

// ---------------- K3: implicit-GEMM bf16 MFMA conv -------------------------------------
// 1D grid, vx=g&7 decomposition: XCD x (round-robin by linear id) sees only hb in
// [8x, 8x+8) -> Wc working set 576KB/XCD, L2-resident.
// LDS sX[6][66][64ch] with channel-rotate swizzle slot=(c+8*(col&7))&63 (8/bank floor).
__global__ __launch_bounds__(256, 3) void k_conv(
    const short* __restrict__ xc, const short* __restrict__ Wc,
    const int* __restrict__ acnt, float* __restrict__ out)
{
    int g = blockIdx.x;
    int vx = g & 7, r = g >> 3;               // 112 blocks per vx
    int hb = vx * 8 + r / 14;
    int band = r - (r / 14) * 14;
    int h = hb >> 4, b = hb & 15;
    int tid = threadIdx.x, lane = tid & 63, w = tid >> 6;
    int y0 = band * 4;
    int cnt = acnt[hb];
    int cntp = (cnt + 31) & ~31;

    __shared__ short sX[6 * 66 * 64];         // 50688 B

    {   // stage 6 rows x 66 cols x 64 ch, fully coalesced 16B chunks
        const short* xb = xc + (size_t)hb * HW_ * 64;
        for (int row = 0; row < 6; ++row) {
            int gy = y0 + row - 1;
            bool yok = (gy >= 0 && gy < H_);
            for (int e = tid; e < 66 * 8; e += 256) {
                int col = e >> 3, ck = e & 7;
                int gx = col - 1;
                bf16x8 v = {0, 0, 0, 0, 0, 0, 0, 0};
                if (yok && gx >= 0 && gx < W_)
                    v = *(const bf16x8*)(xb + ((size_t)(gy * W_ + gx)) * 64 + ck * 8);
                int slot = ((ck << 3) + ((col & 7) << 3)) & 63;
                *(bf16x8*)(sX + (row * 66 + col) * 64 + slot) = v;
            }
        }
    }
    __syncthreads();

    f32x4 acc[4][4];
    #pragma unroll
    for (int i = 0; i < 4; ++i)
        #pragma unroll
        for (int j = 0; j < 4; ++j)
            #pragma unroll
            for (int rr = 0; rr < 4; ++rr) acc[i][j][rr] = 0.f;

    int m = lane & 15, q = lane >> 4;
    const unsigned int* sXu = (const unsigned int*)sX;
    const short* Wh = Wc + (size_t)hb * 9 * 4096;
    int yrow = y0 + w;

    for (int t = 0; t < 9; ++t) {
        int dy = t / 3 - 1, dx = t - (t / 3) * 3 - 1;
        int srow = w + dy + 1;
        int coln = m + dx + 1;
        int sb8 = (coln & 7) << 3;            // col&7 is xt-invariant (xt*16 % 8 == 0)
        const short* Wt = Wh + t * 4096 + m * 64 + q * 8;
        int ub = (srow * 66 + coln) * 32;
        for (int c0 = 0; c0 < cntp; c0 += 32) {
            bf16x8 aF[4], bF[4];
            #pragma unroll
            for (int jt = 0; jt < 4; ++jt)
                aF[jt] = *(const bf16x8*)(Wt + jt * 1024 + c0);
            int slot = (c0 + q * 8 + sb8) & 63;
            #pragma unroll
            for (int xt = 0; xt < 4; ++xt)
                bF[xt] = *(const bf16x8*)&sXu[ub + xt * 512 + (slot >> 1)];
            #pragma unroll
            for (int jt = 0; jt < 4; ++jt)
                #pragma unroll
                for (int xt = 0; xt < 4; ++xt)
                    acc[jt][xt] = __builtin_amdgcn_mfma_f32_16x16x32_bf16(
                        aF[jt], bF[xt], acc[jt][xt], 0, 0, 0);
        }
    }

    #pragma unroll
    for (int xt = 0; xt < 4; ++xt) {
        int xx = xt * 16 + m;
        if (xx < W_) {
            #pragma unroll
            for (int jt = 0; jt < 4; ++jt)
                #pragma unroll
                for (int rr = 0; rr < 4; ++rr) {
                    int j = jt * 16 + q * 4 + rr;         // D: row = quad*4 + reg
                    int oc = j * HEADS_ + h;              // head interleave
                    out[(((size_t)b * C_ + oc) * H_ + yrow) * W_ + xx] = acc[jt][xt][rr];
                }
        }
    }
}

// ---------------- launch ----------------------------------------------------------------
extern "C" void kernel_launch(void* const* d_in, const int* in_sizes, int n_in,
                              void* d_out, int out_size, void* d_ws, size_t ws_size,
                              hipStream_t stream)
{
    const float* x     = (const float*)d_in[0];
    const float* gamma = (const float*)d_in[1];
    const float* beta  = (const float*)d_in[2];
    const float* mean  = (const float*)d_in[3];
    const float* var   = (const float*)d_in[4];
    const float* fc1   = (const float*)d_in[5];
    const float* fc2   = (const float*)d_in[6];
    const float* fc2b  = (const float*)d_in[7];
    const float* convw = (const float*)d_in[8];
    const int*   kptr  = (const int*)d_in[9];

    float* out   = (float*)d_out;
    float* lasso = out + (size_t)B_ * C_ * HW_;

    char* ws = (char*)d_ws;
    size_t off = 0;
    short* xc    = (short*)(ws + off); off += (size_t)HEADS_ * B_ * HW_ * 64 * 2;  // 25.7 MB
    off = (off + 255) & ~(size_t)255;
    float* xavg  = (float*)(ws + off); off += (size_t)B_ * C_ * 4;
    float* maskc = (float*)(ws + off); off += (size_t)HEADS_ * B_ * C_ * 4;
    int*   aidx64= (int*)  (ws + off); off += (size_t)HEADS_ * B_ * 64 * 4;
    int*   acnt  = (int*)  (ws + off); off += (size_t)HEADS_ * B_ * 4;
    off = (off + 255) & ~(size_t)255;
    float* wt2f  = (float*)(ws + off); off += (size_t)HEADS_ * 9 * CPER_ * C_ * 4;  // 2.36 MB
    off = (off + 255) & ~(size_t)255;
    short* Wc    = (short*)(ws + off); off += (size_t)HEADS_ * B_ * 9 * CPER_ * 64 * 2; // 4.72 MB

    hipMemsetAsync(lasso, 0, 4, stream);

    k_wt2<<<(HEADS_ * 9 * CPER_ * C_ + 255) / 256, 256, 0, stream>>>(convw, wt2f);
    k_pool<<<B_ * C_, 64, 0, stream>>>(x, gamma, beta, mean, var, xavg);
    k_se<<<HEADS_ * B_, 256, 0, stream>>>(xavg, fc1, fc2, fc2b, kptr,
                                          maskc, aidx64, acnt, lasso);
    k_wgather<<<dim3(9, HEADS_ * B_), 256, 0, stream>>>(wt2f, maskc, aidx64, acnt, Wc);
    k_bnc<<<dim3(H_, B_), 256, 0, stream>>>(x, gamma, beta, mean, var, aidx64, xc);
    k_conv<<<HEADS_ * B_ * (H_ / 4), 256, 0, stream>>>(xc, Wc, acnt, out);
}

// Round 4
// 194.339 us; speedup vs baseline: 2.5425x; 1.0438x over previous
//
#include <hip/hip_runtime.h>
#include <hip/hip_bf16.h>
#include <math.h>

#define B_     16
#define C_     256
#define H_     56
#define W_     56
#define HEADS_ 4
#define CPER_  64
#define R_     16
#define HW_    (H_*W_)      // 3136
#define BN_EPS_ 1e-5f

typedef short bf16x8 __attribute__((ext_vector_type(8)));
typedef float f32x4  __attribute__((ext_vector_type(4)));

__device__ inline unsigned short f2bf(float f) {
    unsigned int u = __builtin_bit_cast(unsigned int, f);
    u += 0x7fffu + ((u >> 16) & 1u);          // RNE (finite inputs only)
    return (unsigned short)(u >> 16);
}

// ---------------- K0: exact fp32 BN+ReLU+mean per (b,c) plane --------------------------
__global__ __launch_bounds__(64) void k_pool(
    const float* __restrict__ x,
    const float* __restrict__ gamma, const float* __restrict__ beta,
    const float* __restrict__ mean,  const float* __restrict__ var,
    float* __restrict__ xavg)
{
    int plane = blockIdx.x;                   // b*256 + c
    int c = plane & (C_ - 1);
    float s = gamma[c] * rsqrtf(var[c] + BN_EPS_);
    float t = fmaf(-mean[c], s, beta[c]);
    const float4* xp = (const float4*)(x + (size_t)plane * HW_);
    float sum = 0.f;
    for (int i = threadIdx.x; i < HW_ / 4; i += 64) {
        float4 v = xp[i];
        sum += fmaxf(fmaf(v.x, s, t), 0.f) + fmaxf(fmaf(v.y, s, t), 0.f)
             + fmaxf(fmaf(v.z, s, t), 0.f) + fmaxf(fmaf(v.w, s, t), 0.f);
    }
    for (int off = 32; off; off >>= 1) sum += __shfl_down(sum, off, 64);
    if (threadIdx.x == 0) xavg[plane] = sum * (1.f / HW_);
}

// ---------------- K2a: conv_w[h][j][c][t] -> wt2f[h][t][j][c] (fp32, c innermost) -----
__global__ __launch_bounds__(256) void k_wt2(const float* __restrict__ w,
                                             float* __restrict__ wt2f)
{
    int i = blockIdx.x * 256 + threadIdx.x;
    if (i >= HEADS_ * 9 * CPER_ * C_) return;
    int c = i & 255, j = (i >> 8) & 63, ht = i >> 14;
    int h = ht / 9, t = ht - h * 9;
    wt2f[i] = w[((size_t)((h * CPER_ + j) * C_ + c)) * 9 + t];
}

// ---------------- K2: SE gate, exact rank-k threshold, compaction, lasso ---------------
__global__ __launch_bounds__(256) void k_se(
    const float* __restrict__ xavg,
    const float* __restrict__ fc1, const float* __restrict__ fc2,
    const float* __restrict__ fc2b, const int* __restrict__ kptr,
    float* __restrict__ maskc, int* __restrict__ aidx64,
    int* __restrict__ act_cnt, float* __restrict__ lasso)
{
    int hb = blockIdx.x;              // h*B + b
    int h = hb / B_, b = hb - h * B_;
    int tid = threadIdx.x;            // = channel c

    __shared__ float sav[C_], sy1[R_], smask[C_], sred[4], sthr;
    __shared__ int scnt, s_ord[C_];

    sav[tid] = xavg[b * C_ + tid];
    if (tid == 0) scnt = 0;
    __syncthreads();

    if (tid < R_) {
        const float* w = fc1 + (size_t)(h * R_ + tid) * C_;
        float acc = 0.f;
        for (int c2 = 0; c2 < C_; ++c2) acc = fmaf(sav[c2], w[c2], acc);
        sy1[tid] = fmaxf(acc, 0.f);
    }
    __syncthreads();

    const float* w2 = fc2 + (size_t)(h * C_ + tid) * R_;
    float acc = fc2b[h * C_ + tid];
    for (int r = 0; r < R_; ++r) acc = fmaf(sy1[r], w2[r], acc);
    float m = fmaxf(acc, 0.f);
    smask[tid] = m;
    __syncthreads();

    float ls = m;
    for (int off = 32; off > 0; off >>= 1) ls += __shfl_down(ls, off, 64);
    int lane = tid & 63, wv = tid >> 6;
    if (lane == 0) sred[wv] = ls;

    int cl = 0, ce = 0;
    for (int j = 0; j < C_; ++j) {
        float vj = smask[j];
        cl += (vj < m);
        ce += (vj == m);
    }
    if (tid == 0) sthr = -1e30f;
    __syncthreads();
    int k = kptr[0];
    if (k > 0 && cl <= k - 1 && (k - 1) < cl + ce) sthr = m;
    __syncthreads();

    float thr = sthr;
    float mc = (m <= thr) ? 0.f : m;
    maskc[hb * C_ + tid] = mc;
    if (mc != 0.f) {
        int p = atomicAdd(&scnt, 1);          // order-free (all consumers use same list)
        s_ord[p] = tid;
    }
    __syncthreads();
    if (tid < 64) aidx64[hb * 64 + tid] = (tid < scnt) ? s_ord[tid] : 0;  // zero-padded
    if (tid == 0) {
        act_cnt[hb] = scnt;
        atomicAdd(lasso, (sred[0] + sred[1] + sred[2] + sred[3]) * (1.f / (B_ * C_)));
    }
}

// ---------------- K2c: compact+mask weights -> Wc[hb][t][j][slot] bf16, PRE-ROTATED ----
// slot = (c' + 8*(j&7)) & 63  -> k_conv's LDS A-frag reads are 2-way-only (free) and
// staging writes are contiguous.
__global__ __launch_bounds__(256) void k_wgather(
    const float* __restrict__ wt2f, const float* __restrict__ maskc,
    const int* __restrict__ aidx64, const int* __restrict__ acnt,
    short* __restrict__ Wc)
{
    int t = blockIdx.x, hb = blockIdx.y;
    int h = hb >> 4;
    int tid = threadIdx.x;
    int cnt = acnt[hb];
    __shared__ int s_act[64];
    __shared__ float s_mv[64];
    if (tid < 64) {
        int a = aidx64[hb * 64 + tid];
        s_act[tid] = a;
        s_mv[tid]  = (tid < cnt) ? maskc[hb * C_ + a] : 0.f;
    }
    __syncthreads();
    const float* wsrc = wt2f + (size_t)(h * 9 + t) * (CPER_ * C_);
    short* wdst = Wc + (size_t)(hb * 9 + t) * (CPER_ * 64);
    for (int it = 0; it < 16; ++it) {
        int e = it * 256 + tid;
        int cp = e & 63, j = e >> 6;
        float v = wsrc[j * C_ + s_act[cp]] * s_mv[cp];   // mask folded into weight
        int slot = (cp + 8 * (j & 7)) & 63;              // pre-rotate for LDS bank spread
        wdst[j * 64 + slot] = (short)f2bf(v);
    }
}

// ---------------- K1: BN+ReLU+bf16 + per-head channel compaction -> xc[hb][px][64] -----
__global__ __launch_bounds__(256) void k_bnc(
    const float* __restrict__ x,
    const float* __restrict__ gamma, const float* __restrict__ beta,
    const float* __restrict__ mean,  const float* __restrict__ var,
    const int* __restrict__ aidx64, short* __restrict__ xc)
{
    int y = blockIdx.x, b = blockIdx.y;
    int tid = threadIdx.x;
    __shared__ unsigned short T[W_ * 258];    // [x][c], +2 pad breaks stride-256 conflicts
    __shared__ float ss[C_], st[C_];
    __shared__ short sact[256];               // [h][64]

    {
        float s = gamma[tid] * rsqrtf(var[tid] + BN_EPS_);
        ss[tid] = s;
        st[tid] = fmaf(-mean[tid], s, beta[tid]);
        int h = tid >> 6, cp = tid & 63;
        sact[tid] = (short)aidx64[(h * B_ + b) * 64 + cp];
    }
    __syncthreads();

    const float* xrow = x + (size_t)b * C_ * HW_ + y * W_;
    for (int i = tid; i < C_ * 14; i += 256) {    // 14 float4 per channel row
        int c = i / 14, f = i - c * 14;
        float4 v = *(const float4*)(xrow + (size_t)c * HW_ + f * 4);
        float s = ss[c], t = st[c];
        int xb = f * 4;
        T[(xb + 0) * 258 + c] = f2bf(fmaxf(fmaf(v.x, s, t), 0.f));
        T[(xb + 1) * 258 + c] = f2bf(fmaxf(fmaf(v.y, s, t), 0.f));
        T[(xb + 2) * 258 + c] = f2bf(fmaxf(fmaf(v.z, s, t), 0.f));
        T[(xb + 3) * 258 + c] = f2bf(fmaxf(fmaf(v.w, s, t), 0.f));
    }
    __syncthreads();

    unsigned int* ob = (unsigned int*)xc;
    #pragma unroll
    for (int h = 0; h < HEADS_; ++h) {
        size_t obase = ((size_t)(h * B_ + b) * HW_ + (size_t)y * W_) * 32;
        for (int i = tid; i < W_ * 32; i += 256) {    // 56 px x 32 dwords, 7 iters
            int px = i >> 5, d = i & 31;
            unsigned int lo = T[px * 258 + sact[h * 64 + 2 * d]];
            unsigned int hi = T[px * 258 + sact[h * 64 + 2 * d + 1]];
            ob[obase + i] = lo | (hi << 16);
        }
    }
}

// ---------------- K3: implicit-GEMM bf16 MFMA conv, all-resident operands --------------
// Weights: LDS, tap-double-buffered (stage t+1 while computing t; ds_write after MFMAs so
// the vmcnt wait hides behind compute). A-frag = ds_read_b128 from pre-rotated layout.
// Input: B-frags loaded DIRECTLY from xc (pixel-major, channel-contiguous 16B chunks);
// tap-to-tap reuse hits L1/L2. No input staging phase at all. LDS = 16 KB.
__global__ __launch_bounds__(256, 3) void k_conv(
    const short* __restrict__ xc, const short* __restrict__ Wc,
    float* __restrict__ out)
{
    int g = blockIdx.x;
    int vx = g & 7, r = g >> 3;               // XCD-local hb window (Wc/xc L2-resident)
    int hb = vx * 8 + r / 14;
    int band = r - (r / 14) * 14;
    int h = hb >> 4, b = hb & 15;
    int tid = threadIdx.x, lane = tid & 63, wv = tid >> 6;
    int y0 = band * 4;
    int m = lane & 15, q = lane >> 4;

    __shared__ short sW[2][4096];             // 16 KB double buffer, one tap each

    const short* Wh = Wc + (size_t)hb * 9 * 4096;
    const short* xb = xc + (size_t)hb * HW_ * 64;
    int soff = wv * 512 + lane * 8;           // this wave's staging slice (shorts)

    {   // stage tap 0
        bf16x8 w0 = *(const bf16x8*)(Wh + soff);
        bf16x8 w1 = *(const bf16x8*)(Wh + 2048 + soff);
        *(bf16x8*)&sW[0][soff] = w0;
        *(bf16x8*)&sW[0][2048 + soff] = w1;
    }
    __syncthreads();

    f32x4 acc[4][4];                          // [jt][xt]
    #pragma unroll
    for (int i = 0; i < 4; ++i)
        #pragma unroll
        for (int j = 0; j < 4; ++j)
            #pragma unroll
            for (int rr = 0; rr < 4; ++rr) acc[i][j][rr] = 0.f;

    int yrow = y0 + wv;
    int arot = q * 8 + 8 * (m & 7);           // A-frag slot rotation (add c0, &63)

    #pragma unroll
    for (int t = 0; t < 9; ++t) {
        const int dy = t / 3 - 1, dx = t % 3 - 1;
        bf16x8 w0, w1;
        if (t < 8) {                          // prefetch next tap (consumed after MFMAs)
            const short* Wn = Wh + (t + 1) * 4096;
            w0 = *(const bf16x8*)(Wn + soff);
            w1 = *(const bf16x8*)(Wn + 2048 + soff);
        }
        int gy = yrow + dy;
        bool gyok = (unsigned)gy < (unsigned)H_;
        const short* sWc = sW[t & 1];

        #pragma unroll
        for (int c0 = 0; c0 < 64; c0 += 32) {
            bf16x8 aF[4], bF[4];
            #pragma unroll
            for (int jt = 0; jt < 4; ++jt)
                aF[jt] = *(const bf16x8*)&sWc[(jt * 16 + m) * 64 + ((c0 + arot) & 63)];
            #pragma unroll
            for (int xt = 0; xt < 4; ++xt) {
                int gx = xt * 16 + m + dx;
                bf16x8 v = {0, 0, 0, 0, 0, 0, 0, 0};
                if (gyok && (unsigned)gx < (unsigned)W_)
                    v = *(const bf16x8*)(xb + ((size_t)(gy * W_ + gx)) * 64 + c0 + q * 8);
                bF[xt] = v;
            }
            #pragma unroll
            for (int jt = 0; jt < 4; ++jt)
                #pragma unroll
                for (int xt = 0; xt < 4; ++xt)
                    acc[jt][xt] = __builtin_amdgcn_mfma_f32_16x16x32_bf16(
                        aF[jt], bF[xt], acc[jt][xt], 0, 0, 0);
        }
        if (t < 8) {                          // commit prefetched weights to LDS
            *(bf16x8*)&sW[(t + 1) & 1][soff] = w0;
            *(bf16x8*)&sW[(t + 1) & 1][2048 + soff] = w1;
        }
        __syncthreads();
    }

    #pragma unroll
    for (int xt = 0; xt < 4; ++xt) {
        int xx = xt * 16 + m;
        if (xx < W_) {
            #pragma unroll
            for (int jt = 0; jt < 4; ++jt)
                #pragma unroll
                for (int rr = 0; rr < 4; ++rr) {
                    int j = jt * 16 + q * 4 + rr;         // D: row = quad*4 + reg
                    int oc = j * HEADS_ + h;              // head interleave
                    out[(((size_t)b * C_ + oc) * H_ + yrow) * W_ + xx] = acc[jt][xt][rr];
                }
        }
    }
}

// ---------------- launch ----------------------------------------------------------------
extern "C" void kernel_launch(void* const* d_in, const int* in_sizes, int n_in,
                              void* d_out, int out_size, void* d_ws, size_t ws_size,
                              hipStream_t stream)
{
    const float* x     = (const float*)d_in[0];
    const float* gamma = (const float*)d_in[1];
    const float* beta  = (const float*)d_in[2];
    const float* mean  = (const float*)d_in[3];
    const float* var   = (const float*)d_in[4];
    const float* fc1   = (const float*)d_in[5];
    const float* fc2   = (const float*)d_in[6];
    const float* fc2b  = (const float*)d_in[7];
    const float* convw = (const float*)d_in[8];
    const int*   kptr  = (const int*)d_in[9];

    float* out   = (float*)d_out;
    float* lasso = out + (size_t)B_ * C_ * HW_;

    char* ws = (char*)d_ws;
    size_t off = 0;
    short* xc    = (short*)(ws + off); off += (size_t)HEADS_ * B_ * HW_ * 64 * 2;  // 25.7 MB
    off = (off + 255) & ~(size_t)255;
    float* xavg  = (float*)(ws + off); off += (size_t)B_ * C_ * 4;
    float* maskc = (float*)(ws + off); off += (size_t)HEADS_ * B_ * C_ * 4;
    int*   aidx64= (int*)  (ws + off); off += (size_t)HEADS_ * B_ * 64 * 4;
    int*   acnt  = (int*)  (ws + off); off += (size_t)HEADS_ * B_ * 4;
    off = (off + 255) & ~(size_t)255;
    float* wt2f  = (float*)(ws + off); off += (size_t)HEADS_ * 9 * CPER_ * C_ * 4;  // 2.36 MB
    off = (off + 255) & ~(size_t)255;
    short* Wc    = (short*)(ws + off); off += (size_t)HEADS_ * B_ * 9 * CPER_ * 64 * 2; // 4.72 MB

    hipMemsetAsync(lasso, 0, 4, stream);

    k_wt2<<<(HEADS_ * 9 * CPER_ * C_ + 255) / 256, 256, 0, stream>>>(convw, wt2f);
    k_pool<<<B_ * C_, 64, 0, stream>>>(x, gamma, beta, mean, var, xavg);
    k_se<<<HEADS_ * B_, 256, 0, stream>>>(xavg, fc1, fc2, fc2b, kptr,
                                          maskc, aidx64, acnt, lasso);
    k_wgather<<<dim3(9, HEADS_ * B_), 256, 0, stream>>>(wt2f, maskc, aidx64, acnt, Wc);
    k_bnc<<<dim3(H_, B_), 256, 0, stream>>>(x, gamma, beta, mean, var, aidx64, xc);
    k_conv<<<HEADS_ * B_ * (H_ / 4), 256, 0, stream>>>(xc, Wc, out);
}